// Round 4
// baseline (223.767 us; speedup 1.0000x reference)
//
#include <hip/hip_runtime.h>

// Planar NF v4: two kernels.
//  nf_gen (1 block): Wt=[d][k], uhat, G[k][j]=uhat_j.w_k, c_k -> workspace (unchanged, proven).
//  nf_fused (512 blocks, 256 thr, ROWS=128):
//   Phase 1 and 3 read w/uhat/X straight from GLOBAL (VMEM coalescer dedups the
//   8-way lane-shared addresses; tables are L1/L2-hot). LDS holds only P+T+G
//   (~37 KB) -> LDS-pipe demand drops ~44us -> ~6us per CU; 3 barriers total.
//   Per-thread tiles: phase1 4r x 4k, phase3 4r x 8c (x4 col passes).

#define B_ 65536
#define D_ 256
#define ROWS 128
#define GRID (B_ / ROWS)

#define WS_WT 0
#define WS_UH 8192
#define WS_G  16384
#define WS_C  17408

// LDS float offsets (fused): P[32][128] stride 132, T same, then G/c/b
#define P_STR 132
#define T_OFF 4224
#define G_OFF 8448
#define C_OFF 9504
#define BB_OFF 9536
#define LDS_FLOATS 9568

__global__ __launch_bounds__(256) void nf_gen(const float* __restrict__ u_in,
                                              const float* __restrict__ w_in,
                                              float* __restrict__ ws) {
  __shared__ float wTg[8192];  // [d][k]
  __shared__ float ug[8192];   // [j][d]
  __shared__ float wu_s[32], ww_s[32], coefs_s[32];
  const int t = threadIdx.x;
  {
    const int k = t & 31, d0 = (t >> 5) * 32;
    const float4* wp = (const float4*)(w_in + k * 256 + d0);
#pragma unroll
    for (int q = 0; q < 8; ++q) {
      float4 v = wp[q];
      wTg[(d0 + q * 4 + 0) * 32 + k] = v.x;
      wTg[(d0 + q * 4 + 1) * 32 + k] = v.y;
      wTg[(d0 + q * 4 + 2) * 32 + k] = v.z;
      wTg[(d0 + q * 4 + 3) * 32 + k] = v.w;
    }
#pragma unroll
    for (int q = 0; q < 8; ++q)
      ((float4*)ug)[t + 256 * q] = ((const float4*)u_in)[t + 256 * q];
  }
  __syncthreads();
  const int k = t & 31, jg = t >> 5;  // this thread: row k, cols jg*4..+4
  float m1[4] = {0.f, 0.f, 0.f, 0.f}, m2[4] = {0.f, 0.f, 0.f, 0.f};
#pragma unroll 4
  for (int dc = 0; dc < 64; ++dc) {
    float wk[4];
    float4 wj[4], uj[4];
#pragma unroll
    for (int i = 0; i < 4; ++i) wk[i] = wTg[(dc * 4 + i) * 32 + k];
#pragma unroll
    for (int i = 0; i < 4; ++i) wj[i] = *(const float4*)&wTg[(dc * 4 + i) * 32 + jg * 4];
#pragma unroll
    for (int i = 0; i < 4; ++i) uj[i] = *(const float4*)&ug[(jg * 4 + i) * 256 + dc * 4];
#pragma unroll
    for (int i = 0; i < 4; ++i) {
      m1[i] = fmaf(uj[i].x, wk[0], m1[i]);
      m1[i] = fmaf(uj[i].y, wk[1], m1[i]);
      m1[i] = fmaf(uj[i].z, wk[2], m1[i]);
      m1[i] = fmaf(uj[i].w, wk[3], m1[i]);
    }
    const float* w0 = (const float*)&wj[0];
    const float* w1 = (const float*)&wj[1];
    const float* w2 = (const float*)&wj[2];
    const float* w3 = (const float*)&wj[3];
#pragma unroll
    for (int i = 0; i < 4; ++i) {
      m2[i] = fmaf(w0[i], wk[0], m2[i]);
      m2[i] = fmaf(w1[i], wk[1], m2[i]);
      m2[i] = fmaf(w2[i], wk[2], m2[i]);
      m2[i] = fmaf(w3[i], wk[3], m2[i]);
    }
  }
  if ((k >> 2) == jg) {  // holds diagonal element j==k
    wu_s[k] = m1[k & 3];
    ww_s[k] = m2[k & 3];
  }
  __syncthreads();
  if (t < 32) {
    float wu = wu_s[t], ww = ww_s[t];
    float sp = fmaxf(wu, 0.f) + log1pf(__expf(-fabsf(wu)));
    coefs_s[t] = (sp - 1.f - wu) / ww;
    ws[WS_C + t] = sp - 1.f;  // c_k = w_k.uhat_k
  }
  __syncthreads();
#pragma unroll
  for (int i = 0; i < 4; ++i)
    ws[WS_G + k * 32 + jg * 4 + i] = fmaf(coefs_s[jg * 4 + i], m2[i], m1[i]);
  {
    const int k2 = t >> 3, d0 = (t & 7) * 32;
    const float ck = coefs_s[k2];
    const float4* up = (const float4*)(u_in + k2 * 256 + d0);
    const float4* wp2 = (const float4*)(w_in + k2 * 256 + d0);
    float4* od = (float4*)(ws + WS_UH + k2 * 256 + d0);
#pragma unroll
    for (int q = 0; q < 8; ++q) {
      float4 uv = up[q], wv = wp2[q];
      uv.x = fmaf(ck, wv.x, uv.x);
      uv.y = fmaf(ck, wv.y, uv.y);
      uv.z = fmaf(ck, wv.z, uv.z);
      uv.w = fmaf(ck, wv.w, uv.w);
      od[q] = uv;
    }
  }
#pragma unroll
  for (int q = 0; q < 8; ++q)
    ((float4*)(ws + WS_WT))[t + 256 * q] = ((const float4*)wTg)[t + 256 * q];
}

__global__ __launch_bounds__(256) void nf_fused(const float* __restrict__ X,
                                                const float* __restrict__ b_in,
                                                const float* __restrict__ ws,
                                                float* __restrict__ out) {
  __shared__ float lds[LDS_FLOATS];  // P@0 [32][132], T@T_OFF [32][132], G/c/b

  const int t = threadIdx.x;
  const int row0 = blockIdx.x * ROWS;
  const int xoff = (t >> 6) * 32 + ((t >> 3) & 7) * 4;  // 4-row base (wave owns 32 rows)
  const int kq4 = (t & 7) * 4;                          // phase1 k base (8 lanes share)
  const int cq8 = (t & 7) * 8;                          // phase3 col base

  // ---------------- phase 1: p[4r][4k] = X . w  (all operands from global) ----
  float p[4][4];
#pragma unroll
  for (int a = 0; a < 4; ++a)
#pragma unroll
    for (int b2 = 0; b2 < 4; ++b2) p[a][b2] = 0.f;
  {
    const float* wbase = ws + WS_WT + kq4;               // [d][32] table, lane-shared
    const float* xb = X + (size_t)(row0 + xoff) * 256;   // 4 rows, this lane
#pragma unroll 2
    for (int dq = 0; dq < 64; ++dq) {
      float4 wr[4];
#pragma unroll
      for (int i = 0; i < 4; ++i) wr[i] = *(const float4*)(wbase + (dq * 4 + i) * 32);
      float4 xr[4];
#pragma unroll
      for (int a = 0; a < 4; ++a) xr[a] = *(const float4*)(xb + a * 256 + dq * 4);
#pragma unroll
      for (int a = 0; a < 4; ++a) {
        const float xf[4] = {xr[a].x, xr[a].y, xr[a].z, xr[a].w};
#pragma unroll
        for (int i = 0; i < 4; ++i) {
          p[a][0] = fmaf(xf[i], wr[i].x, p[a][0]);
          p[a][1] = fmaf(xf[i], wr[i].y, p[a][1]);
          p[a][2] = fmaf(xf[i], wr[i].z, p[a][2]);
          p[a][3] = fmaf(xf[i], wr[i].w, p[a][3]);
        }
      }
    }
  }

  // ---------------- P dump [k][r] + stage G/c/b into LDS ----------------
#pragma unroll
  for (int b2 = 0; b2 < 4; ++b2)
    *(float4*)&lds[(kq4 + b2) * P_STR + xoff] =
        make_float4(p[0][b2], p[1][b2], p[2][b2], p[3][b2]);
#pragma unroll
  for (int i = 0; i < 4; ++i) {
    const int e = t * 4 + i;
    lds[G_OFF + (e >> 5) * 33 + (e & 31)] = ws[WS_G + e];
  }
  if (t < 32) {
    lds[C_OFF + t] = ws[WS_C + t];
    lds[BB_OFF + t] = b_in[t];
  }
  __syncthreads();

  // ---------------- recurrence: one row per thread ----------------
  if (t < 128) {
    float pfull[32];
#pragma unroll
    for (int j = 0; j < 32; ++j) pfull[j] = lds[j * P_STR + t] + lds[BB_OFF + j];
    float tvv[32];
#pragma unroll
    for (int kk = 0; kk < 32; ++kk) {
      float la = pfull[kk], lb = 0.f;
      const float* gp = &lds[G_OFF + kk * 33];
#pragma unroll
      for (int j = 0; j + 1 < kk; j += 2) {
        la = fmaf(tvv[j], gp[j], la);
        lb = fmaf(tvv[j + 1], gp[j + 1], lb);
      }
      if (kk & 1) la = fmaf(tvv[kk - 1], gp[kk - 1], la);
      float lin = la + lb;
      float e = __expf(2.f * lin);
      float tk = 1.f - 2.f / (e + 1.f);
      tvv[kk] = tk;
      lds[T_OFF + kk * P_STR + t] = tk;  // T [k][r]
      float val = fabsf(fmaf(1.f - tk * tk, lds[C_OFF + kk], 1.f)) + 1e-8f;
      out[(size_t)B_ * D_ + (size_t)kk * B_ + row0 + t] = __logf(val);
    }
  }
  __syncthreads();

  // ---------------- phase 3: z = X + T . uhat (4r x 8c, 4 col passes) --------
  for (int cbk = 0; cbk < 4; ++cbk) {
    const int c0 = cbk * 64 + cq8;
    float acc[4][8];
#pragma unroll
    for (int a = 0; a < 4; ++a) {
      const float4 x0 = *(const float4*)(X + (size_t)(row0 + xoff + a) * 256 + c0);
      const float4 x1 = *(const float4*)(X + (size_t)(row0 + xoff + a) * 256 + c0 + 4);
      acc[a][0] = x0.x; acc[a][1] = x0.y; acc[a][2] = x0.z; acc[a][3] = x0.w;
      acc[a][4] = x1.x; acc[a][5] = x1.y; acc[a][6] = x1.z; acc[a][7] = x1.w;
    }
#pragma unroll 4
    for (int kk = 0; kk < 32; ++kk) {
      float4 t4 = *(const float4*)&lds[T_OFF + kk * P_STR + xoff];  // 4 rows of T
      float4 u0 = *(const float4*)(ws + WS_UH + kk * 256 + c0);     // global, L1/L2-hot
      float4 u1 = *(const float4*)(ws + WS_UH + kk * 256 + c0 + 4);
      const float tr[4] = {t4.x, t4.y, t4.z, t4.w};
      const float uk[8] = {u0.x, u0.y, u0.z, u0.w, u1.x, u1.y, u1.z, u1.w};
#pragma unroll
      for (int a = 0; a < 4; ++a)
#pragma unroll
        for (int b2 = 0; b2 < 8; ++b2) acc[a][b2] = fmaf(tr[a], uk[b2], acc[a][b2]);
    }
#pragma unroll
    for (int a = 0; a < 4; ++a) {
      float4* op = (float4*)(out + (size_t)(row0 + xoff + a) * 256 + c0);
      op[0] = make_float4(acc[a][0], acc[a][1], acc[a][2], acc[a][3]);
      op[1] = make_float4(acc[a][4], acc[a][5], acc[a][6], acc[a][7]);
    }
  }
}

extern "C" void kernel_launch(void* const* d_in, const int* in_sizes, int n_in,
                              void* d_out, int out_size, void* d_ws, size_t ws_size,
                              hipStream_t stream) {
  const float* X = (const float*)d_in[0];
  // d_in[1] = h : unused by the math
  const float* u = (const float*)d_in[2];
  const float* w = (const float*)d_in[3];
  const float* b = (const float*)d_in[4];
  float* out = (float*)d_out;
  float* ws = (float*)d_ws;

  nf_gen<<<1, 256, 0, stream>>>(u, w, ws);
  nf_fused<<<GRID, 256, 0, stream>>>(X, b, ws, out);
}